// Round 1
// baseline (298.383 us; speedup 1.0000x reference)
//
#include <hip/hip_runtime.h>
#include <hip/hip_bf16.h>
#include <cstdint>
#include <cstddef>

typedef __bf16 bf16;
typedef __bf16 bf16x8 __attribute__((ext_vector_type(8)));
typedef float f32x4 __attribute__((ext_vector_type(4)));

#define NB 2
#define SEQ 2048
#define DM 1024
#define MTOK 4096   // NB*SEQ
#define DL 256
#define NH 16
#define HD 64

#define LOG2E 1.4426950408889634f
#define DECAY_C 1.0e-4f   // LAMBDA_DECAY * TIME_STEP

// ---------------- prep: f32 -> bf16 elementwise ----------------
__global__ __launch_bounds__(256) void cvt_f32_bf16(const float* __restrict__ in,
                                                    bf16* __restrict__ out, int n) {
  int i = (blockIdx.x * 256 + threadIdx.x) * 4;
  if (i + 3 < n) {
    float4 v = *reinterpret_cast<const float4*>(in + i);
    bf16 o[4] __attribute__((aligned(8)));
    o[0] = (bf16)v.x; o[1] = (bf16)v.y; o[2] = (bf16)v.z; o[3] = (bf16)v.w;
    *reinterpret_cast<uint2*>(out + i) = *reinterpret_cast<const uint2*>(o);
  }
}

// ---------------- prep: transpose (+optional add) f32 -> bf16 ----------------
// out[c][r] = bf16( in0[r][c] + (in1 ? in1[r][c] : 0) )
__global__ __launch_bounds__(256) void transpose_bf16(const float* __restrict__ in0,
                                                      const float* __restrict__ in1,
                                                      bf16* __restrict__ out, int R, int C) {
  __shared__ float tile[32][33];
  int c0 = blockIdx.x * 32, r0 = blockIdx.y * 32;
  int tx = threadIdx.x, ty = threadIdx.y;  // 32 x 8
#pragma unroll
  for (int i = 0; i < 4; ++i) {
    int r = r0 + ty + 8 * i;
    float v = in0[(size_t)r * C + c0 + tx];
    if (in1) v += in1[(size_t)r * C + c0 + tx];
    tile[ty + 8 * i][tx] = v;
  }
  __syncthreads();
#pragma unroll
  for (int i = 0; i < 4; ++i) {
    out[(size_t)(c0 + ty + 8 * i) * R + r0 + tx] = (bf16)tile[tx][ty + 8 * i];
  }
}

// ---------------- bf16 MFMA GEMM: C = A @ B, with Bt = B^T ([N][K] row-major) ----
// EPI: 0 = bf16 row-major C; 1 = bf16 + f32 row-major C; 2 = bf16 transposed C (Ct[N][M]);
//      3 = f32 row-major only
template <int EPI>
__global__ __launch_bounds__(256) void gemm_bt(const bf16* __restrict__ A,
                                               const bf16* __restrict__ Bt,
                                               bf16* __restrict__ Cb,
                                               float* __restrict__ Cf,
                                               int M, int N, int K) {
  // padded LDS: pitch 40 elems (80B) -> ds_read_b128 spreads banks (2-way, free)
  __shared__ __align__(16) bf16 As[128][40];
  __shared__ __align__(16) bf16 Bs[128][40];
  const int tid = threadIdx.x;
  const int lane = tid & 63;
  const int wv = tid >> 6;          // 4 waves, 2x2
  const int wr = wv >> 1, wc = wv & 1;
  const int row0 = blockIdx.x * 128, col0 = blockIdx.y * 128;
  const int l15 = lane & 15;
  const int kq = (lane >> 4) * 8;

  f32x4 acc[4][4] = {};

  for (int k0 = 0; k0 < K; k0 += 32) {
    __syncthreads();
    // stage A-tile [128][32] and Bt-tile [128][32]; 2x 16B chunks per thread each
#pragma unroll
    for (int i = 0; i < 2; ++i) {
      int c = tid + i * 256;
      int r = c >> 2, kc = c & 3;
      *reinterpret_cast<uint4*>(&As[r][kc * 8]) =
          *reinterpret_cast<const uint4*>(A + (size_t)(row0 + r) * K + k0 + kc * 8);
      *reinterpret_cast<uint4*>(&Bs[r][kc * 8]) =
          *reinterpret_cast<const uint4*>(Bt + (size_t)(col0 + r) * K + k0 + kc * 8);
    }
    __syncthreads();
    bf16x8 af[4], bfr[4];
#pragma unroll
    for (int m = 0; m < 4; ++m)
      af[m] = *reinterpret_cast<const bf16x8*>(&As[wr * 64 + m * 16 + l15][kq]);
#pragma unroll
    for (int n = 0; n < 4; ++n)
      bfr[n] = *reinterpret_cast<const bf16x8*>(&Bs[wc * 64 + n * 16 + l15][kq]);
#pragma unroll
    for (int m = 0; m < 4; ++m)
#pragma unroll
      for (int n = 0; n < 4; ++n)
        acc[m][n] = __builtin_amdgcn_mfma_f32_16x16x32_bf16(af[m], bfr[n], acc[m][n], 0, 0, 0);
  }

  // C/D frag layout: col = lane&15, row = (lane>>4)*4 + r  [m89-verified]
  const int rbase = row0 + wr * 64 + (lane >> 4) * 4;
  const int cbase = col0 + wc * 64 + l15;
#pragma unroll
  for (int m = 0; m < 4; ++m) {
#pragma unroll
    for (int n = 0; n < 4; ++n) {
      if constexpr (EPI == 2) {
        bf16 tmp[4] __attribute__((aligned(8)));
#pragma unroll
        for (int r = 0; r < 4; ++r) tmp[r] = (bf16)acc[m][n][r];
        *reinterpret_cast<uint2*>(Cb + (size_t)(cbase + n * 16) * M + (rbase + m * 16)) =
            *reinterpret_cast<const uint2*>(tmp);
      } else {
#pragma unroll
        for (int r = 0; r < 4; ++r) {
          int rr = rbase + m * 16 + r;
          int cc = cbase + n * 16;
          float v = acc[m][n][r];
          if constexpr (EPI == 0 || EPI == 1) Cb[(size_t)rr * N + cc] = (bf16)v;
          if constexpr (EPI == 1 || EPI == 3) Cf[(size_t)rr * N + cc] = v;
        }
      }
    }
  }
}

// ---------------- flash attention with time decay ----------------
// Q [4096][1024] bf16, Kr [4096][1024] bf16, Vt [1024][4096] bf16 (d-major), Ctx [4096][1024] bf16
__global__ __launch_bounds__(256) void attn_kernel(const bf16* __restrict__ Q,
                                                   const bf16* __restrict__ Kr,
                                                   const bf16* __restrict__ Vt,
                                                   bf16* __restrict__ Ctx) {
  __shared__ __align__(16) bf16 Ks[64][72];
  __shared__ __align__(16) bf16 Vs[64][72];       // Vs[d][key]
  __shared__ __align__(16) bf16 Ps[4][16][72];    // per-wave P tile
  const int qt = blockIdx.x, h = blockIdx.y, b = blockIdx.z;
  const int tid = threadIdx.x, lane = tid & 63, wv = tid >> 6;
  const int l15 = lane & 15, lg = lane >> 4;
  const int qbase = qt * 64 + wv * 16;  // seq index of this wave's first q row
  const size_t tok0 = (size_t)b * SEQ;

  // Q fragments (held in registers across the whole loop)
  bf16x8 qf[2];
  {
    const bf16* qp = Q + (tok0 + qbase + l15) * DM + h * HD + lg * 8;
    qf[0] = *reinterpret_cast<const bf16x8*>(qp);
    qf[1] = *reinterpret_cast<const bf16x8*>(qp + 32);
  }

  f32x4 oacc[4] = {};
  float mrow[4], lrow[4];
#pragma unroll
  for (int r = 0; r < 4; ++r) { mrow[r] = -1e30f; lrow[r] = 0.f; }

  const float scale = 1.0f / 32.0f;  // 1/(sqrt(1024)+1e-8)

  for (int t = 0; t < SEQ / 64; ++t) {
    const int key0 = t * 64;
    __syncthreads();
    // stage K rows [64][64] and V^T rows [64 d][64 key]
#pragma unroll
    for (int i = 0; i < 2; ++i) {
      int c = tid + i * 256;
      int r = c >> 3, kc = c & 7;
      *reinterpret_cast<uint4*>(&Ks[r][kc * 8]) =
          *reinterpret_cast<const uint4*>(Kr + (tok0 + key0 + r) * DM + h * HD + kc * 8);
      *reinterpret_cast<uint4*>(&Vs[r][kc * 8]) =
          *reinterpret_cast<const uint4*>(Vt + (size_t)(h * HD + r) * MTOK + tok0 + key0 + kc * 8);
    }
    __syncthreads();

    // scores: S[16 q][64 keys] per wave
    f32x4 sc[4] = {};
#pragma unroll
    for (int nf = 0; nf < 4; ++nf) {
#pragma unroll
      for (int ks = 0; ks < 2; ++ks) {
        bf16x8 kf = *reinterpret_cast<const bf16x8*>(&Ks[nf * 16 + l15][ks * 32 + lg * 8]);
        sc[nf] = __builtin_amdgcn_mfma_f32_16x16x32_bf16(qf[ks], kf, sc[nf], 0, 0, 0);
      }
    }

    // scale * decay, online softmax
    float p[4][4];
    float mt[4];
#pragma unroll
    for (int r = 0; r < 4; ++r) mt[r] = -1e30f;
#pragma unroll
    for (int nf = 0; nf < 4; ++nf) {
#pragma unroll
      for (int r = 0; r < 4; ++r) {
        float qi = (float)(qbase + lg * 4 + r);
        float kj = (float)(key0 + nf * 16 + l15);
        float dd = fabsf(qi - kj);
        float v = sc[nf][r] * scale * exp2f(-(DECAY_C * LOG2E) * dd);
        p[nf][r] = v;
        mt[r] = fmaxf(mt[r], v);
      }
    }
#pragma unroll
    for (int r = 0; r < 4; ++r) {
#pragma unroll
      for (int off = 1; off < 16; off <<= 1)
        mt[r] = fmaxf(mt[r], __shfl_xor(mt[r], off));
      float mnew = fmaxf(mrow[r], mt[r]);
      float alpha = exp2f((mrow[r] - mnew) * LOG2E);
      mrow[r] = mnew;
      lrow[r] *= alpha;
#pragma unroll
      for (int nf = 0; nf < 4; ++nf) oacc[nf][r] *= alpha;
      float ps = 0.f;
#pragma unroll
      for (int nf = 0; nf < 4; ++nf) {
        float e = exp2f((p[nf][r] - mnew) * LOG2E);
        p[nf][r] = e;
        ps += e;
      }
#pragma unroll
      for (int off = 1; off < 16; off <<= 1) ps += __shfl_xor(ps, off);
      lrow[r] += ps;
    }

    // redistribute P through LDS (C-layout -> A-layout)
#pragma unroll
    for (int nf = 0; nf < 4; ++nf)
#pragma unroll
      for (int r = 0; r < 4; ++r)
        Ps[wv][lg * 4 + r][nf * 16 + l15] = (bf16)p[nf][r];
    __syncthreads();

    bf16x8 pa[2];
    pa[0] = *reinterpret_cast<const bf16x8*>(&Ps[wv][l15][lg * 8]);
    pa[1] = *reinterpret_cast<const bf16x8*>(&Ps[wv][l15][32 + lg * 8]);
#pragma unroll
    for (int nf = 0; nf < 4; ++nf) {
#pragma unroll
      for (int ks = 0; ks < 2; ++ks) {
        bf16x8 vf = *reinterpret_cast<const bf16x8*>(&Vs[nf * 16 + l15][ks * 32 + lg * 8]);
        oacc[nf] = __builtin_amdgcn_mfma_f32_16x16x32_bf16(pa[ks], vf, oacc[nf], 0, 0, 0);
      }
    }
  }

  // normalize + write ctx (bf16, row-major [token][1024])
#pragma unroll
  for (int r = 0; r < 4; ++r) {
    float inv = 1.0f / lrow[r];
#pragma unroll
    for (int nf = 0; nf < 4; ++nf) {
      Ctx[(tok0 + qbase + lg * 4 + r) * DM + h * HD + nf * 16 + l15] =
          (bf16)(oacc[nf][r] * inv);
    }
  }
}

// ---------------- launch ----------------
extern "C" void kernel_launch(void* const* d_in, const int* in_sizes, int n_in,
                              void* d_out, int out_size, void* d_ws, size_t ws_size,
                              hipStream_t stream) {
  const float* x   = (const float*)d_in[0];
  const float* Wq  = (const float*)d_in[1];
  const float* Wk  = (const float*)d_in[2];
  const float* Wv  = (const float*)d_in[3];
  const float* Wo  = (const float*)d_in[4];
  const float* Wdn = (const float*)d_in[5];
  const float* Wuk = (const float*)d_in[6];
  const float* Wuv = (const float*)d_in[7];
  float* out0 = (float*)d_out;                     // [4096][1024] f32
  float* out_lat = out0 + (size_t)MTOK * DM;       // [4096][256]  f32

  char* ws = (char*)d_ws;
  bf16* xbf   = (bf16*)(ws + 0);                          // 8 MiB; reused as ctx
  bf16* qbf   = (bf16*)(ws + (size_t)(8u << 20));         // 8 MiB
  bf16* kbuf  = (bf16*)(ws + (size_t)(16u << 20));        // 8 MiB: kvsum, then k_rec
  bf16* vT    = (bf16*)(ws + (size_t)(24u << 20));        // 8 MiB: v_rec^T [1024][4096]
  bf16* latbf = (bf16*)(ws + (size_t)(32u << 20));        // 2 MiB
  bf16* WqT   = (bf16*)(ws + (size_t)(34u << 20));        // 2 MiB
  bf16* WkvT  = (bf16*)(ws + (size_t)(36u << 20));        // 2 MiB
  bf16* WoT   = (bf16*)(ws + (size_t)(38u << 20));        // 2 MiB
  bf16* WdnT  = (bf16*)(ws + (size_t)(40u << 20));        // 512 KiB [256][1024]
  bf16* WukT  = (bf16*)(ws + (size_t)(40u << 20) + (512u << 10));  // 512 KiB [1024][256]
  bf16* WuvT  = (bf16*)(ws + (size_t)(41u << 20));        // 512 KiB [1024][256]
  bf16* ctx   = xbf;

  cvt_f32_bf16<<<4096, 256, 0, stream>>>(x, xbf, MTOK * DM);
  dim3 tb(32, 8);
  transpose_bf16<<<dim3(32, 32), tb, 0, stream>>>(Wq, nullptr, WqT, DM, DM);
  transpose_bf16<<<dim3(32, 32), tb, 0, stream>>>(Wk, Wv, WkvT, DM, DM);   // Wk+Wv folded
  transpose_bf16<<<dim3(32, 32), tb, 0, stream>>>(Wo, nullptr, WoT, DM, DM);
  transpose_bf16<<<dim3(8, 32), tb, 0, stream>>>(Wdn, nullptr, WdnT, DM, DL);
  transpose_bf16<<<dim3(32, 8), tb, 0, stream>>>(Wuk, nullptr, WukT, DL, DM);
  transpose_bf16<<<dim3(32, 8), tb, 0, stream>>>(Wuv, nullptr, WuvT, DL, DM);

  // q = x @ Wq
  gemm_bt<0><<<dim3(32, 8), 256, 0, stream>>>(xbf, WqT, qbf, nullptr, MTOK, DM, DM);
  // kvsum = x @ (Wk+Wv)
  gemm_bt<0><<<dim3(32, 8), 256, 0, stream>>>(xbf, WkvT, kbuf, nullptr, MTOK, DM, DM);
  // latent = kvsum @ W_down  -> bf16 scratch + f32 OUTPUT 1
  gemm_bt<1><<<dim3(32, 2), 256, 0, stream>>>(kbuf, WdnT, latbf, out_lat, MTOK, DL, DM);
  // k_rec = latent @ W_up_k  (overwrites kvsum, now dead)
  gemm_bt<0><<<dim3(32, 8), 256, 0, stream>>>(latbf, WukT, kbuf, nullptr, MTOK, DM, DL);
  // v_rec^T = (latent @ W_up_v)^T
  gemm_bt<2><<<dim3(32, 8), 256, 0, stream>>>(latbf, WuvT, vT, nullptr, MTOK, DM, DL);
  // attention
  attn_kernel<<<dim3(SEQ / 64, NH, NB), 256, 0, stream>>>(qbf, kbuf, vT, ctx);
  // out0 = ctx @ Wo
  gemm_bt<3><<<dim3(32, 8), 256, 0, stream>>>(ctx, WoT, nullptr, out0, MTOK, DM, DM);

  (void)in_sizes; (void)n_in; (void)out_size; (void)ws_size;
}

// Round 2
// 211.897 us; speedup vs baseline: 1.4082x; 1.4082x over previous
//
#include <hip/hip_runtime.h>
#include <hip/hip_bf16.h>
#include <cstdint>
#include <cstddef>

typedef __bf16 bf16;
typedef __bf16 bf16x8 __attribute__((ext_vector_type(8)));
typedef float f32x4 __attribute__((ext_vector_type(4)));

#define NB 2
#define SEQ 2048
#define DM 1024
#define MTOK 4096   // NB*SEQ
#define DL 256
#define NH 16
#define HD 64

#define LOG2E 1.4426950408889634f

__device__ __forceinline__ void gload16(const void* g, void* l) {
  __builtin_amdgcn_global_load_lds((const __attribute__((address_space(1))) void*)g,
                                   (__attribute__((address_space(3))) void*)l, 16, 0, 0);
}

// ---------------- prep: f32 -> bf16 elementwise ----------------
__global__ __launch_bounds__(256) void cvt_f32_bf16(const float* __restrict__ in,
                                                    bf16* __restrict__ out, int n) {
  int i = (blockIdx.x * 256 + threadIdx.x) * 4;
  if (i + 3 < n) {
    float4 v = *reinterpret_cast<const float4*>(in + i);
    bf16 o[4] __attribute__((aligned(8)));
    o[0] = (bf16)v.x; o[1] = (bf16)v.y; o[2] = (bf16)v.z; o[3] = (bf16)v.w;
    *reinterpret_cast<uint2*>(out + i) = *reinterpret_cast<const uint2*>(o);
  }
}

// ---------------- prep: transpose (+optional add) f32 -> bf16 ----------------
__global__ __launch_bounds__(256) void transpose_bf16(const float* __restrict__ in0,
                                                      const float* __restrict__ in1,
                                                      bf16* __restrict__ out, int R, int C) {
  __shared__ float tile[32][33];
  int c0 = blockIdx.x * 32, r0 = blockIdx.y * 32;
  int tx = threadIdx.x, ty = threadIdx.y;  // 32 x 8
#pragma unroll
  for (int i = 0; i < 4; ++i) {
    int r = r0 + ty + 8 * i;
    float v = in0[(size_t)r * C + c0 + tx];
    if (in1) v += in1[(size_t)r * C + c0 + tx];
    tile[ty + 8 * i][tx] = v;
  }
  __syncthreads();
#pragma unroll
  for (int i = 0; i < 4; ++i) {
    out[(size_t)(c0 + ty + 8 * i) * R + r0 + tx] = (bf16)tile[tx][ty + 8 * i];
  }
}

// ---------------- bf16 MFMA GEMM (m97-style staging): C = A @ B, Bt = B^T ----
// EPI: 0 = bf16 C; 1 = bf16 + f32 C; 2 = bf16 transposed C (Ct[N][M]); 3 = f32 C
template <int EPI>
__global__ __launch_bounds__(256) void gemm_bt(const bf16* __restrict__ A,
                                               const bf16* __restrict__ Bt,
                                               bf16* __restrict__ Cb,
                                               float* __restrict__ Cf,
                                               int M, int N, int K) {
  __shared__ __align__(16) bf16 As[128 * 32];
  __shared__ __align__(16) bf16 Bs[128 * 32];
  const int tid = threadIdx.x;
  const int lane = tid & 63;
  const int wv = tid >> 6;          // 4 waves, 2x2
  const int wr = wv >> 1, wc = wv & 1;
  const int row0 = blockIdx.x * 128, col0 = blockIdx.y * 128;
  const int l15 = lane & 15;
  const int kq = (lane >> 4) * 8;

  // staging: 512 chunks of 16B per tile per matrix; chunk c: row=c>>2, quarter=c&3
  const bf16* aSrc[2]; const bf16* bSrc[2]; bf16* aDst[2]; bf16* bDst[2];
#pragma unroll
  for (int i = 0; i < 2; ++i) {
    int c = tid + i * 256;
    aSrc[i] = A + (size_t)(row0 + (c >> 2)) * K + (c & 3) * 8;
    bSrc[i] = Bt + (size_t)(col0 + (c >> 2)) * K + (c & 3) * 8;
    aDst[i] = &As[c * 8];
    bDst[i] = &Bs[c * 8];
  }

  f32x4 acc[4][4] = {};

  for (int k0 = 0; k0 < K; k0 += 32) {
    __syncthreads();
    gload16(aSrc[0], aDst[0]); gload16(aSrc[1], aDst[1]);
    gload16(bSrc[0], bDst[0]); gload16(bSrc[1], bDst[1]);
#pragma unroll
    for (int i = 0; i < 2; ++i) { aSrc[i] += 32; bSrc[i] += 32; }
    __syncthreads();
    bf16x8 af[4], bfr[4];
#pragma unroll
    for (int m = 0; m < 4; ++m)
      af[m] = *reinterpret_cast<const bf16x8*>(&As[(wr * 64 + m * 16 + l15) * 32 + kq]);
#pragma unroll
    for (int n = 0; n < 4; ++n)
      bfr[n] = *reinterpret_cast<const bf16x8*>(&Bs[(wc * 64 + n * 16 + l15) * 32 + kq]);
#pragma unroll
    for (int m = 0; m < 4; ++m)
#pragma unroll
      for (int n = 0; n < 4; ++n)
        acc[m][n] = __builtin_amdgcn_mfma_f32_16x16x32_bf16(af[m], bfr[n], acc[m][n], 0, 0, 0);
  }

  // C/D frag layout: col = lane&15, row = (lane>>4)*4 + r
  const int rbase = row0 + wr * 64 + (lane >> 4) * 4;
  const int cbase = col0 + wc * 64 + l15;
#pragma unroll
  for (int m = 0; m < 4; ++m) {
#pragma unroll
    for (int n = 0; n < 4; ++n) {
      if constexpr (EPI == 2) {
        bf16 tmp[4] __attribute__((aligned(8)));
#pragma unroll
        for (int r = 0; r < 4; ++r) tmp[r] = (bf16)acc[m][n][r];
        *reinterpret_cast<uint2*>(Cb + (size_t)(cbase + n * 16) * M + (rbase + m * 16)) =
            *reinterpret_cast<const uint2*>(tmp);
      } else {
#pragma unroll
        for (int r = 0; r < 4; ++r) {
          int rr = rbase + m * 16 + r;
          int cc = cbase + n * 16;
          float v = acc[m][n][r];
          if constexpr (EPI == 0 || EPI == 1) Cb[(size_t)rr * N + cc] = (bf16)v;
          if constexpr (EPI == 1 || EPI == 3) Cf[(size_t)rr * N + cc] = v;
        }
      }
    }
  }
}

// ---------------- flash attention, swapped orientation, no-max softmax ----------------
// Q [4096][1024], Kr [4096][1024], Vt [1024][4096] (d-major), Ctx [4096][1024]
__global__ __launch_bounds__(256) void attn_kernel(const bf16* __restrict__ Q,
                                                   const bf16* __restrict__ Kr,
                                                   const bf16* __restrict__ Vt,
                                                   bf16* __restrict__ Ctx) {
  __shared__ __align__(16) bf16 Ks[64 * 64];   // XOR-swizzled 16B chunks
  __shared__ __align__(16) bf16 Vs[64 * 64];   // Vs[d][key], swizzled
  __shared__ __align__(16) bf16 Ps[4][16][72]; // per-wave P^T staging, padded pitch
  const int qt = blockIdx.x, h = blockIdx.y, b = blockIdx.z;
  const int tid = threadIdx.x, lane = tid & 63, wv = tid >> 6;
  const int l15 = lane & 15, lg = lane >> 4;
  const int qbase = qt * 64 + wv * 16;  // this wave's q rows: qbase..qbase+15
  const size_t tok0 = (size_t)b * SEQ;

  // Q as B-fragment (col=q=l15, k=d=lg*8+j) -- contiguous row-major load
  bf16x8 qf[2];
  {
    const bf16* qp = Q + (tok0 + qbase + l15) * DM + h * HD + lg * 8;
    qf[0] = *reinterpret_cast<const bf16x8*>(qp);
    qf[1] = *reinterpret_cast<const bf16x8*>(qp + 32);
  }

  // staging: 512 chunks each; chunk c: row=c>>3, col-chunk cc=c&7, src chunk cc^(row&7)
  const bf16* kSrc[2]; const bf16* vSrc[2];
  bf16* kDst[2]; bf16* vDst[2];
#pragma unroll
  for (int i = 0; i < 2; ++i) {
    int c = tid + i * 256;
    int r = c >> 3;
    int cc = (c & 7) ^ (r & 7);
    kSrc[i] = Kr + (tok0 + r) * DM + h * HD + cc * 8;
    vSrc[i] = Vt + (size_t)(h * HD + r) * MTOK + tok0 + cc * 8;
    kDst[i] = &Ks[c * 8];
    vDst[i] = &Vs[c * 8];
  }

  f32x4 oacc[4] = {};   // O^T frags: col=q=l15, rows d = nf*16 + lg*4 + r
  float lsum = 0.f;
  float dec[4][4];      // scale*LOG2E*exp(-lambda*dt*|key-q|) per held element

  const float DEC2C = (1.0f / 32.0f) * LOG2E;  // 1/(sqrt(1024)+1e-8) ~ 1/32
  const float NC2   = -1.0e-4f * LOG2E;        // -lambda*dt in log2 domain
  const float E64   = 0.99362048f;             // exp(-64e-4)
  const float IE64  = 1.00642051f;             // exp(+64e-4)
  const int ib = -qbase - l15 + lg * 4;        // key - q = key0 + nf*16 + r + ib

  for (int t = 0; t < SEQ / 64; ++t) {
    const int key0 = t * 64;
    __syncthreads();
    gload16(kSrc[0], kDst[0]); gload16(kSrc[1], kDst[1]);
    gload16(vSrc[0], vDst[0]); gload16(vSrc[1], vDst[1]);
    kSrc[0] += 64 * DM; kSrc[1] += 64 * DM;
    vSrc[0] += 64;      vSrc[1] += 64;

    // decay update (all branches wave-uniform)
    {
      bool before = (key0 + 63 < qbase);   // all keys strictly before q window
      bool afterp = (key0 >= qbase + 79);  // prev tile already fully after window
      if (t == 0 || (!before && !afterp)) {
#pragma unroll
        for (int nf = 0; nf < 4; ++nf)
#pragma unroll
          for (int r = 0; r < 4; ++r) {
            float df = (float)(key0 + ib + nf * 16 + r);
            dec[nf][r] = DEC2C * exp2f(NC2 * fabsf(df));
          }
      } else {
        float mlt = before ? IE64 : E64;
#pragma unroll
        for (int nf = 0; nf < 4; ++nf)
#pragma unroll
          for (int r = 0; r < 4; ++r) dec[nf][r] *= mlt;
      }
    }
    __syncthreads();

    // S^T[key][q] = K @ Q^T  (A=K frag, B=Q frag)
    f32x4 sc[4] = {};
#pragma unroll
    for (int ks = 0; ks < 2; ++ks) {
#pragma unroll
      for (int nf = 0; nf < 4; ++nf) {
        int row = nf * 16 + l15;
        int off = row * 64 + (((ks * 4 + lg) ^ (row & 7)) * 8);
        bf16x8 kf = *reinterpret_cast<const bf16x8*>(&Ks[off]);
        sc[nf] = __builtin_amdgcn_mfma_f32_16x16x32_bf16(kf, qf[ks], sc[nf], 0, 0, 0);
      }
    }

    // p = exp2(s * dec)  (no max subtraction: scores bounded), pack, partial sum
#pragma unroll
    for (int nf = 0; nf < 4; ++nf) {
      bf16 t4[4] __attribute__((aligned(8)));
#pragma unroll
      for (int r = 0; r < 4; ++r) {
        float p = exp2f(sc[nf][r] * dec[nf][r]);
        lsum += p;
        t4[r] = (bf16)p;
      }
      *reinterpret_cast<uint2*>(&Ps[wv][l15][nf * 16 + lg * 4]) =
          *reinterpret_cast<const uint2*>(t4);
    }

    // P^T as B-fragment (col=q=l15, k=key=lg*8+j): wave-local LDS round-trip
    bf16x8 pb[2];
#pragma unroll
    for (int ks = 0; ks < 2; ++ks)
      pb[ks] = *reinterpret_cast<const bf16x8*>(&Ps[wv][l15][ks * 32 + lg * 8]);

    // O^T += V^T @ P^T  (A=V^T frag, B=P^T frag)
#pragma unroll
    for (int ks = 0; ks < 2; ++ks) {
#pragma unroll
      for (int nf = 0; nf < 4; ++nf) {
        int row = nf * 16 + l15;
        int off = row * 64 + (((ks * 4 + lg) ^ (row & 7)) * 8);
        bf16x8 vf = *reinterpret_cast<const bf16x8*>(&Vs[off]);
        oacc[nf] = __builtin_amdgcn_mfma_f32_16x16x32_bf16(vf, pb[ks], oacc[nf], 0, 0, 0);
      }
    }
  }

  // full row sum (4 lg groups hold disjoint key subsets of the same q)
  lsum += __shfl_xor(lsum, 16);
  lsum += __shfl_xor(lsum, 32);
  float inv = 1.0f / lsum;
#pragma unroll
  for (int nf = 0; nf < 4; ++nf) {
    bf16 o4[4] __attribute__((aligned(8)));
#pragma unroll
    for (int r = 0; r < 4; ++r) o4[r] = (bf16)(oacc[nf][r] * inv);
    *reinterpret_cast<uint2*>(Ctx + (tok0 + qbase + l15) * DM + h * HD + nf * 16 + lg * 4) =
        *reinterpret_cast<const uint2*>(o4);
  }
}

// ---------------- launch ----------------
extern "C" void kernel_launch(void* const* d_in, const int* in_sizes, int n_in,
                              void* d_out, int out_size, void* d_ws, size_t ws_size,
                              hipStream_t stream) {
  const float* x   = (const float*)d_in[0];
  const float* Wq  = (const float*)d_in[1];
  const float* Wk  = (const float*)d_in[2];
  const float* Wv  = (const float*)d_in[3];
  const float* Wo  = (const float*)d_in[4];
  const float* Wdn = (const float*)d_in[5];
  const float* Wuk = (const float*)d_in[6];
  const float* Wuv = (const float*)d_in[7];
  float* out0 = (float*)d_out;                     // [4096][1024] f32
  float* out_lat = out0 + (size_t)MTOK * DM;       // [4096][256]  f32

  char* ws = (char*)d_ws;
  bf16* xbf   = (bf16*)(ws + 0);                          // 8 MiB; reused as ctx
  bf16* qbf   = (bf16*)(ws + (size_t)(8u << 20));         // 8 MiB
  bf16* kbuf  = (bf16*)(ws + (size_t)(16u << 20));        // 8 MiB: kvsum, then k_rec
  bf16* vT    = (bf16*)(ws + (size_t)(24u << 20));        // 8 MiB: v_rec^T [1024][4096]
  bf16* latbf = (bf16*)(ws + (size_t)(32u << 20));        // 2 MiB
  bf16* WqT   = (bf16*)(ws + (size_t)(34u << 20));        // 2 MiB
  bf16* WkvT  = (bf16*)(ws + (size_t)(36u << 20));        // 2 MiB
  bf16* WoT   = (bf16*)(ws + (size_t)(38u << 20));        // 2 MiB
  bf16* WdnT  = (bf16*)(ws + (size_t)(40u << 20));        // 512 KiB [256][1024]
  bf16* WukT  = (bf16*)(ws + (size_t)(40u << 20) + (512u << 10));  // 512 KiB
  bf16* WuvT  = (bf16*)(ws + (size_t)(41u << 20));        // 512 KiB
  bf16* ctx   = xbf;

  cvt_f32_bf16<<<4096, 256, 0, stream>>>(x, xbf, MTOK * DM);
  dim3 tb(32, 8);
  transpose_bf16<<<dim3(32, 32), tb, 0, stream>>>(Wq, nullptr, WqT, DM, DM);
  transpose_bf16<<<dim3(32, 32), tb, 0, stream>>>(Wk, Wv, WkvT, DM, DM);   // Wk+Wv folded
  transpose_bf16<<<dim3(32, 32), tb, 0, stream>>>(Wo, nullptr, WoT, DM, DM);
  transpose_bf16<<<dim3(8, 32), tb, 0, stream>>>(Wdn, nullptr, WdnT, DM, DL);
  transpose_bf16<<<dim3(32, 8), tb, 0, stream>>>(Wuk, nullptr, WukT, DL, DM);
  transpose_bf16<<<dim3(32, 8), tb, 0, stream>>>(Wuv, nullptr, WuvT, DL, DM);

  // q = x @ Wq
  gemm_bt<0><<<dim3(32, 8), 256, 0, stream>>>(xbf, WqT, qbf, nullptr, MTOK, DM, DM);
  // kvsum = x @ (Wk+Wv)
  gemm_bt<0><<<dim3(32, 8), 256, 0, stream>>>(xbf, WkvT, kbuf, nullptr, MTOK, DM, DM);
  // latent = kvsum @ W_down  -> bf16 scratch + f32 OUTPUT 1
  gemm_bt<1><<<dim3(32, 2), 256, 0, stream>>>(kbuf, WdnT, latbf, out_lat, MTOK, DL, DM);
  // k_rec = latent @ W_up_k  (overwrites kvsum, now dead)
  gemm_bt<0><<<dim3(32, 8), 256, 0, stream>>>(latbf, WukT, kbuf, nullptr, MTOK, DM, DL);
  // v_rec^T = (latent @ W_up_v)^T
  gemm_bt<2><<<dim3(32, 8), 256, 0, stream>>>(latbf, WuvT, vT, nullptr, MTOK, DM, DL);
  // attention
  attn_kernel<<<dim3(SEQ / 64, NH, NB), 256, 0, stream>>>(qbf, kbuf, vT, ctx);
  // out0 = ctx @ Wo
  gemm_bt<3><<<dim3(32, 8), 256, 0, stream>>>(ctx, WoT, nullptr, out0, MTOK, DM, DM);

  (void)in_sizes; (void)n_in; (void)out_size; (void)ws_size;
}

// Round 3
// 147.947 us; speedup vs baseline: 2.0168x; 1.4322x over previous
//
#include <hip/hip_runtime.h>
#include <hip/hip_bf16.h>
#include <cstdint>
#include <cstddef>

typedef __bf16 bf16;
typedef __bf16 bf16x8 __attribute__((ext_vector_type(8)));
typedef float f32x4 __attribute__((ext_vector_type(4)));

#define NB 2
#define SEQ 2048
#define DM 1024
#define MTOK 4096   // NB*SEQ
#define DL 256
#define NH 16
#define HD 64

#define LOG2E 1.4426950408889634f

__device__ __forceinline__ void gload16(const void* g, void* l) {
  __builtin_amdgcn_global_load_lds((const __attribute__((address_space(1))) void*)g,
                                   (__attribute__((address_space(3))) void*)l, 16, 0, 0);
}
__device__ __forceinline__ float fast_exp2(float x) {
  float r; asm("v_exp_f32 %0, %1" : "=v"(r) : "v"(x)); return r;
}
__device__ __forceinline__ uint32_t cvt_pk_bf16(float lo, float hi) {
  uint32_t r; asm("v_cvt_pk_bf16_f32 %0, %1, %2" : "=v"(r) : "v"(lo), "v"(hi)); return r;
}

// ================= fused prep kernel =================
__device__ __forceinline__ void transpose_dev(const float* __restrict__ in0,
                                              const float* __restrict__ in1,
                                              bf16* __restrict__ out, int R, int C,
                                              int c0, int r0, int tid, float (*tile)[33]) {
  int tx = tid & 31, ty = tid >> 5;  // 32 x 8
#pragma unroll
  for (int i = 0; i < 4; ++i) {
    int r = r0 + ty + 8 * i;
    float v = in0[(size_t)r * C + c0 + tx];
    if (in1) v += in1[(size_t)r * C + c0 + tx];
    tile[ty + 8 * i][tx] = v;
  }
  __syncthreads();
#pragma unroll
  for (int i = 0; i < 4; ++i)
    out[(size_t)(c0 + ty + 8 * i) * R + r0 + tx] = (bf16)tile[tx][ty + 8 * i];
}

__device__ __forceinline__ void cvt8_dev(const float* __restrict__ in, bf16* __restrict__ out,
                                         int blk, int tid) {
  int i = (blk * 256 + tid) * 8;
  float4 a = *reinterpret_cast<const float4*>(in + i);
  float4 b = *reinterpret_cast<const float4*>(in + i + 4);
  uint4 u;
  u.x = cvt_pk_bf16(a.x, a.y); u.y = cvt_pk_bf16(a.z, a.w);
  u.z = cvt_pk_bf16(b.x, b.y); u.w = cvt_pk_bf16(b.z, b.w);
  *reinterpret_cast<uint4*>(out + i) = u;
}

__device__ __forceinline__ void sum8_dev(const float* __restrict__ in0, const float* __restrict__ in1,
                                         bf16* __restrict__ out, int blk, int tid) {
  int i = (blk * 256 + tid) * 8;
  float4 a0 = *reinterpret_cast<const float4*>(in0 + i);
  float4 b0 = *reinterpret_cast<const float4*>(in0 + i + 4);
  float4 a1 = *reinterpret_cast<const float4*>(in1 + i);
  float4 b1 = *reinterpret_cast<const float4*>(in1 + i + 4);
  uint4 u;
  u.x = cvt_pk_bf16(a0.x + a1.x, a0.y + a1.y); u.y = cvt_pk_bf16(a0.z + a1.z, a0.w + a1.w);
  u.z = cvt_pk_bf16(b0.x + b1.x, b0.y + b1.y); u.w = cvt_pk_bf16(b0.z + b1.z, b0.w + b1.w);
  *reinterpret_cast<uint4*>(out + i) = u;
}

__global__ __launch_bounds__(256) void prep_kernel(const float* __restrict__ x,
                                                   const float* __restrict__ Wq,
                                                   const float* __restrict__ Wk,
                                                   const float* __restrict__ Wv,
                                                   const float* __restrict__ Wo,
                                                   const float* __restrict__ Wdn,
                                                   const float* __restrict__ Wuk,
                                                   const float* __restrict__ Wuv,
                                                   bf16* xbf, bf16* WqT, bf16* WoT, bf16* WdnT,
                                                   bf16* WukT, bf16* WuvT, bf16* Wkv) {
  __shared__ float tile[32][33];
  int id = blockIdx.x, tid = threadIdx.x;
  if (id < 2048) { cvt8_dev(x, xbf, id, tid); return; }
  id -= 2048;
  if (id < 1024) { transpose_dev(Wq, nullptr, WqT, 1024, 1024, (id & 31) * 32, (id >> 5) * 32, tid, tile); return; }
  id -= 1024;
  if (id < 1024) { transpose_dev(Wo, nullptr, WoT, 1024, 1024, (id & 31) * 32, (id >> 5) * 32, tid, tile); return; }
  id -= 1024;
  if (id < 256) { transpose_dev(Wdn, nullptr, WdnT, 1024, 256, (id & 7) * 32, (id >> 3) * 32, tid, tile); return; }
  id -= 256;
  if (id < 256) { transpose_dev(Wuk, nullptr, WukT, 256, 1024, (id & 31) * 32, (id >> 5) * 32, tid, tile); return; }
  id -= 256;
  if (id < 256) { transpose_dev(Wuv, nullptr, WuvT, 256, 1024, (id & 31) * 32, (id >> 5) * 32, tid, tile); return; }
  id -= 256;
  sum8_dev(Wk, Wv, Wkv, id, tid);  // 512 blocks: Wkv = bf16(Wk+Wv) row-major
}

// ================= 128x128 MFMA GEMM, 2-phase dbuf =================
// EPI: 0 = bf16 row-major; 1 = bf16 + f32 row-major; 3 = f32 row-major;
//      4 = split up-proj: col<1024 -> bf16 row (stride DM) to Cb, else transposed to Ct (stride MTOK)
template <int EPI>
__device__ __forceinline__ void gemm128(const bf16* __restrict__ A, const bf16* __restrict__ Bt,
                                        bf16* __restrict__ Cb, float* __restrict__ Cf,
                                        bf16* __restrict__ Ct,
                                        int M, int N, int K, int bx, int by,
                                        bf16* As, bf16* Bs) {
  const int tid = threadIdx.x;
  const int lane = tid & 63;
  const int wv = tid >> 6;
  const int wr = wv >> 1, wc = wv & 1;
  const int row0 = bx * 128, col0 = by * 128;
  const int l15 = lane & 15;
  const int kq = (lane >> 4) * 8;

  const bf16* aS = A + (size_t)(row0 + (tid >> 2)) * K + (tid & 3) * 8;
  const bf16* bS = Bt + (size_t)(col0 + (tid >> 2)) * K + (tid & 3) * 8;
  const int d0 = tid * 8, d1 = tid * 8 + 2048;

  // prologue: stage k0=0 into buf 0
  gload16(aS, As + d0); gload16(aS + (size_t)64 * K, As + d1);
  gload16(bS, Bs + d0); gload16(bS + (size_t)64 * K, Bs + d1);
  aS += 32; bS += 32;

  f32x4 acc[4][4] = {};
  int cur = 0;
  for (int k0 = 0; k0 < K; k0 += 32) {
    __syncthreads();
    if (k0 + 32 < K) {
      const int nx = (cur ^ 1) * 4096;
      gload16(aS, As + nx + d0); gload16(aS + (size_t)64 * K, As + nx + d1);
      gload16(bS, Bs + nx + d0); gload16(bS + (size_t)64 * K, Bs + nx + d1);
      aS += 32; bS += 32;
    }
    const bf16* Ab = As + cur * 4096;
    const bf16* Bb = Bs + cur * 4096;
    bf16x8 af[4], bfr[4];
#pragma unroll
    for (int m = 0; m < 4; ++m)
      af[m] = *reinterpret_cast<const bf16x8*>(&Ab[(wr * 64 + m * 16 + l15) * 32 + kq]);
#pragma unroll
    for (int n = 0; n < 4; ++n)
      bfr[n] = *reinterpret_cast<const bf16x8*>(&Bb[(wc * 64 + n * 16 + l15) * 32 + kq]);
#pragma unroll
    for (int m = 0; m < 4; ++m)
#pragma unroll
      for (int n = 0; n < 4; ++n)
        acc[m][n] = __builtin_amdgcn_mfma_f32_16x16x32_bf16(af[m], bfr[n], acc[m][n], 0, 0, 0);
    cur ^= 1;
  }

  const int rbase = row0 + wr * 64 + (lane >> 4) * 4;
  const int cbase = col0 + wc * 64 + l15;
#pragma unroll
  for (int m = 0; m < 4; ++m) {
#pragma unroll
    for (int n = 0; n < 4; ++n) {
      if constexpr (EPI == 4) {
        if (col0 < 1024) {
#pragma unroll
          for (int r = 0; r < 4; ++r)
            Cb[(size_t)(rbase + m * 16 + r) * DM + (cbase + n * 16)] = (bf16)acc[m][n][r];
        } else {
          uint2 w;
          w.x = cvt_pk_bf16(acc[m][n][0], acc[m][n][1]);
          w.y = cvt_pk_bf16(acc[m][n][2], acc[m][n][3]);
          *reinterpret_cast<uint2*>(Ct + (size_t)(cbase + n * 16 - 1024) * MTOK + (rbase + m * 16)) = w;
        }
      } else {
#pragma unroll
        for (int r = 0; r < 4; ++r) {
          int rr = rbase + m * 16 + r;
          int cc = cbase + n * 16;
          float v = acc[m][n][r];
          if constexpr (EPI == 0 || EPI == 1) Cb[(size_t)rr * N + cc] = (bf16)v;
          if constexpr (EPI == 1 || EPI == 3) Cf[(size_t)rr * N + cc] = v;
        }
      }
    }
  }
}

// ================= 64x64 MFMA GEMM, 2-phase dbuf =================
template <int EPI>
__device__ __forceinline__ void gemm64(const bf16* __restrict__ A, const bf16* __restrict__ Bt,
                                       bf16* __restrict__ Cb, float* __restrict__ Cf,
                                       int M, int N, int K, int bx, int by,
                                       bf16* As, bf16* Bs) {
  const int tid = threadIdx.x;
  const int lane = tid & 63;
  const int wv = tid >> 6;
  const int wr = wv >> 1, wc = wv & 1;
  const int row0 = bx * 64, col0 = by * 64;
  const int l15 = lane & 15;
  const int kq = (lane >> 4) * 8;

  const bf16* aS = A + (size_t)(row0 + (tid >> 2)) * K + (tid & 3) * 8;
  const bf16* bS = Bt + (size_t)(col0 + (tid >> 2)) * K + (tid & 3) * 8;
  const int d0 = tid * 8;

  gload16(aS, As + d0); gload16(bS, Bs + d0);
  aS += 32; bS += 32;

  f32x4 acc[2][2] = {};
  int cur = 0;
  for (int k0 = 0; k0 < K; k0 += 32) {
    __syncthreads();
    if (k0 + 32 < K) {
      const int nx = (cur ^ 1) * 2048;
      gload16(aS, As + nx + d0); gload16(bS, Bs + nx + d0);
      aS += 32; bS += 32;
    }
    const bf16* Ab = As + cur * 2048;
    const bf16* Bb = Bs + cur * 2048;
    bf16x8 af[2], bfr[2];
#pragma unroll
    for (int m = 0; m < 2; ++m)
      af[m] = *reinterpret_cast<const bf16x8*>(&Ab[(wr * 32 + m * 16 + l15) * 32 + kq]);
#pragma unroll
    for (int n = 0; n < 2; ++n)
      bfr[n] = *reinterpret_cast<const bf16x8*>(&Bb[(wc * 32 + n * 16 + l15) * 32 + kq]);
#pragma unroll
    for (int m = 0; m < 2; ++m)
#pragma unroll
      for (int n = 0; n < 2; ++n)
        acc[m][n] = __builtin_amdgcn_mfma_f32_16x16x32_bf16(af[m], bfr[n], acc[m][n], 0, 0, 0);
    cur ^= 1;
  }

  const int rbase = row0 + wr * 32 + (lane >> 4) * 4;
  const int cbase = col0 + wc * 32 + l15;
#pragma unroll
  for (int m = 0; m < 2; ++m)
#pragma unroll
    for (int n = 0; n < 2; ++n)
#pragma unroll
      for (int r = 0; r < 4; ++r) {
        int rr = rbase + m * 16 + r;
        int cc = cbase + n * 16;
        float v = acc[m][n][r];
        if constexpr (EPI == 0 || EPI == 1) Cb[(size_t)rr * N + cc] = (bf16)v;
        if constexpr (EPI == 1) Cf[(size_t)rr * N + cc] = v;
      }
}

// ================= GEMM launch wrappers =================
__global__ __launch_bounds__(256) void gemm_q_w(const bf16* __restrict__ xbf, const bf16* __restrict__ WqT,
                                                bf16* qbf, const bf16* __restrict__ WdnT,
                                                const bf16* __restrict__ Wkv, bf16* WkvdT) {
  __shared__ __align__(16) bf16 As[2 * 4096];
  __shared__ __align__(16) bf16 Bs[2 * 4096];
  int id = blockIdx.x;
  if (id < 256)
    gemm128<0>(xbf, WqT, qbf, nullptr, nullptr, MTOK, DM, DM, id >> 3, id & 7, As, Bs);
  else {
    int j = id - 256;  // 16 blocks: WkvdT[256][1024] = Wdn^T @ (Wk+Wv)^T
    gemm128<0>(WdnT, Wkv, WkvdT, nullptr, nullptr, DL, DM, DM, j >> 3, j & 7, As, Bs);
  }
}

__global__ __launch_bounds__(256) void gemm_latent(const bf16* __restrict__ xbf,
                                                   const bf16* __restrict__ WkvdT,
                                                   bf16* latbf, float* out_lat) {
  __shared__ __align__(16) bf16 As[2 * 2048];
  __shared__ __align__(16) bf16 Bs[2 * 2048];
  int id = blockIdx.x;  // 256 blocks: 64 x 4
  gemm64<1>(xbf, WkvdT, latbf, out_lat, MTOK, DL, DM, id >> 2, id & 3, As, Bs);
}

__global__ __launch_bounds__(256) void gemm_up(const bf16* __restrict__ latbf,
                                               const bf16* __restrict__ WupT,
                                               bf16* kbuf, bf16* vT) {
  __shared__ __align__(16) bf16 As[2 * 4096];
  __shared__ __align__(16) bf16 Bs[2 * 4096];
  int id = blockIdx.x;  // 512 blocks: 32 x 16 (cols 0-1023 -> k_rec, 1024-2047 -> v^T)
  gemm128<4>(latbf, WupT, kbuf, nullptr, vT, MTOK, 2048, DL, id >> 4, id & 15, As, Bs);
}

__global__ __launch_bounds__(256) void gemm_out(const bf16* __restrict__ ctx,
                                                const bf16* __restrict__ WoT, float* out0) {
  __shared__ __align__(16) bf16 As[2 * 4096];
  __shared__ __align__(16) bf16 Bs[2 * 4096];
  int id = blockIdx.x;  // 256 blocks: 32 x 8
  gemm128<3>(ctx, WoT, nullptr, out0, nullptr, MTOK, DM, DM, id >> 3, id & 7, As, Bs);
}

// ================= flash attention: 2-phase dbuf, no-max softmax, MFMA row-sum =================
__global__ __launch_bounds__(256) void attn_kernel(const bf16* __restrict__ Q,
                                                   const bf16* __restrict__ Kr,
                                                   const bf16* __restrict__ Vt,
                                                   bf16* __restrict__ Ctx) {
  __shared__ __align__(16) bf16 Ks[2 * 4096];
  __shared__ __align__(16) bf16 Vs[2 * 4096];
  __shared__ __align__(16) bf16 Ps[4096];      // 4 waves x 16 q x 64 keys, XOR-swizzled, pitch 64
  const int qt = blockIdx.x, h = blockIdx.y, b = blockIdx.z;
  const int tid = threadIdx.x, lane = tid & 63, wv = tid >> 6;
  const int l15 = lane & 15, lg = lane >> 4;
  const int qbase = qt * 64 + wv * 16;
  const size_t tok0 = (size_t)b * SEQ;

  bf16x8 qf[2];
  {
    const bf16* qp = Q + (tok0 + qbase + l15) * DM + h * HD + lg * 8;
    qf[0] = *reinterpret_cast<const bf16x8*>(qp);
    qf[1] = *reinterpret_cast<const bf16x8*>(qp + 32);
  }

  // staging sources (XOR-swizzled source, linear LDS dest)
  const int c1 = tid + 256;
  const int r0s = tid >> 3, r1s = c1 >> 3;
  const int cc0 = (tid & 7) ^ (r0s & 7), cc1 = (c1 & 7) ^ (r1s & 7);
  const bf16* kS0 = Kr + (tok0 + r0s) * DM + h * HD + cc0 * 8;
  const bf16* kS1 = Kr + (tok0 + r1s) * DM + h * HD + cc1 * 8;
  const bf16* vS0 = Vt + (size_t)(h * HD + r0s) * MTOK + tok0 + cc0 * 8;
  const bf16* vS1 = Vt + (size_t)(h * HD + r1s) * MTOK + tok0 + cc1 * 8;
  const int d0 = tid * 8, d1 = tid * 8 + 2048;

  // prologue: stage tile 0 into buf 0
  gload16(kS0, Ks + d0); gload16(kS1, Ks + d1);
  gload16(vS0, Vs + d0); gload16(vS1, Vs + d1);
  kS0 += 64 * DM; kS1 += 64 * DM; vS0 += 64; vS1 += 64;

  // loop-invariant LDS offsets
  int koff[2][4], poffw[4], poffr[2];
  const int hsw = l15 & 7;
#pragma unroll
  for (int ks = 0; ks < 2; ++ks)
#pragma unroll
    for (int nf = 0; nf < 4; ++nf) {
      int row = nf * 16 + l15;
      koff[ks][nf] = row * 64 + (((ks * 4 + lg) ^ (row & 7)) * 8);
    }
  const int psBase = wv * 1024 + l15 * 64;
#pragma unroll
  for (int nf = 0; nf < 4; ++nf)
    poffw[nf] = psBase + (((nf * 2 + (lg >> 1)) ^ hsw) * 8) + (lg & 1) * 4;
#pragma unroll
  for (int ks = 0; ks < 2; ++ks)
    poffr[ks] = psBase + (((ks * 4 + lg) ^ hsw) * 8);

  bf16x8 ones;
#pragma unroll
  for (int j = 0; j < 8; ++j) ones[j] = (bf16)1.0f;

  f32x4 oacc[4] = {};
  f32x4 lacc = {};
  float dec[4][4];
  const float DEC2C = (1.0f / 32.0f) * LOG2E;   // 1/(sqrt(1024)+1e-8) * log2(e)
  const float NC2 = -1.0e-4f * LOG2E;           // -lambda*dt in log2 domain
  const float E64 = 0.99362048f, IE64 = 1.00642051f;
  const int ib = -qbase - l15 + lg * 4;         // key - q = key0 + nf*16 + r + ib

  int cur = 0;
  for (int t = 0; t < SEQ / 64; ++t) {
    const int key0 = t * 64;
    __syncthreads();   // buf[cur] staged; prev reads drained
    if (t + 1 < SEQ / 64) {
      const int nx = (cur ^ 1) * 4096;
      gload16(kS0, Ks + nx + d0); gload16(kS1, Ks + nx + d1);
      gload16(vS0, Vs + nx + d0); gload16(vS1, Vs + nx + d1);
      kS0 += 64 * DM; kS1 += 64 * DM; vS0 += 64; vS1 += 64;
    }
    // decay coefficients (wave-uniform branch)
    {
      bool before = (key0 + 63 < qbase);
      bool afterp = (key0 >= qbase + 79);
      if (t == 0 || (!before && !afterp)) {
#pragma unroll
        for (int nf = 0; nf < 4; ++nf)
#pragma unroll
          for (int r = 0; r < 4; ++r) {
            float df = (float)(key0 + ib + nf * 16 + r);
            dec[nf][r] = DEC2C * fast_exp2(NC2 * fabsf(df));
          }
      } else {
        float mlt = before ? IE64 : E64;
#pragma unroll
        for (int nf = 0; nf < 4; ++nf)
#pragma unroll
          for (int r = 0; r < 4; ++r) dec[nf][r] *= mlt;
      }
    }
    const int kb = cur * 4096;

    // S^T[key][q] = K @ Q^T
    f32x4 sc[4] = {};
#pragma unroll
    for (int ks = 0; ks < 2; ++ks)
#pragma unroll
      for (int nf = 0; nf < 4; ++nf) {
        bf16x8 kf = *reinterpret_cast<const bf16x8*>(&Ks[kb + koff[ks][nf]]);
        sc[nf] = __builtin_amdgcn_mfma_f32_16x16x32_bf16(kf, qf[ks], sc[nf], 0, 0, 0);
      }

    // p = exp2(s * dec); pack to bf16 pairs, store to swizzled Ps
#pragma unroll
    for (int nf = 0; nf < 4; ++nf) {
      float p0 = fast_exp2(sc[nf][0] * dec[nf][0]);
      float p1 = fast_exp2(sc[nf][1] * dec[nf][1]);
      float p2 = fast_exp2(sc[nf][2] * dec[nf][2]);
      float p3 = fast_exp2(sc[nf][3] * dec[nf][3]);
      uint2 w;
      w.x = cvt_pk_bf16(p0, p1);
      w.y = cvt_pk_bf16(p2, p3);
      *reinterpret_cast<uint2*>(&Ps[poffw[nf]]) = w;
    }
    bf16x8 pb[2];
    pb[0] = *reinterpret_cast<const bf16x8*>(&Ps[poffr[0]]);
    pb[1] = *reinterpret_cast<const bf16x8*>(&Ps[poffr[1]]);

    // O^T += V^T @ P^T ; row-sums via ones-MFMA
#pragma unroll
    for (int ks = 0; ks < 2; ++ks) {
#pragma unroll
      for (int nf = 0; nf < 4; ++nf) {
        bf16x8 vf = *reinterpret_cast<const bf16x8*>(&Vs[kb + koff[ks][nf]]);
        oacc[nf] = __builtin_amdgcn_mfma_f32_16x16x32_bf16(vf, pb[ks], oacc[nf], 0, 0, 0);
      }
      lacc = __builtin_amdgcn_mfma_f32_16x16x32_bf16(ones, pb[ks], lacc, 0, 0, 0);
    }
    cur ^= 1;
  }

  const float inv = 1.0f / lacc[0];
#pragma unroll
  for (int nf = 0; nf < 4; ++nf) {
    uint2 w;
    w.x = cvt_pk_bf16(oacc[nf][0] * inv, oacc[nf][1] * inv);
    w.y = cvt_pk_bf16(oacc[nf][2] * inv, oacc[nf][3] * inv);
    *reinterpret_cast<uint2*>(Ctx + (tok0 + qbase + l15) * DM + h * HD + nf * 16 + lg * 4) = w;
  }
}

// ================= launch =================
extern "C" void kernel_launch(void* const* d_in, const int* in_sizes, int n_in,
                              void* d_out, int out_size, void* d_ws, size_t ws_size,
                              hipStream_t stream) {
  const float* x   = (const float*)d_in[0];
  const float* Wq  = (const float*)d_in[1];
  const float* Wk  = (const float*)d_in[2];
  const float* Wv  = (const float*)d_in[3];
  const float* Wo  = (const float*)d_in[4];
  const float* Wdn = (const float*)d_in[5];
  const float* Wuk = (const float*)d_in[6];
  const float* Wuv = (const float*)d_in[7];
  float* out0 = (float*)d_out;                     // [4096][1024] f32
  float* out_lat = out0 + (size_t)MTOK * DM;       // [4096][256]  f32

  char* ws = (char*)d_ws;
  const size_t MB = 1u << 20;
  bf16* xbf   = (bf16*)(ws + 0);            // 8 MiB; reused as ctx after latent GEMM
  bf16* qbf   = (bf16*)(ws + 8 * MB);       // 8 MiB
  bf16* kbuf  = (bf16*)(ws + 16 * MB);      // 8 MiB total region:
  bf16* Wkv   = kbuf;                       //   [16,18) Wkv bf16 (dead after gemm_q_w)
  bf16* WkvdT = (bf16*)(ws + 18 * MB);      //   [18,18.5) WkvdT (dead after gemm_latent)
                                            //   then whole [16,24) = k_rec
  bf16* vT    = (bf16*)(ws + 24 * MB);      // 8 MiB: v_rec^T [1024][4096]
  bf16* latbf = (bf16*)(ws + 32 * MB);      // 2 MiB
  bf16* WqT   = (bf16*)(ws + 34 * MB);      // 2 MiB
  bf16* WoT   = (bf16*)(ws + 36 * MB);      // 2 MiB
  bf16* WdnT  = (bf16*)(ws + 38 * MB);      // 512 KiB [256][1024]
  bf16* WukT  = (bf16*)(ws + 38 * MB + 512 * 1024);  // 512 KiB [1024][256]
  bf16* WuvT  = (bf16*)(ws + 39 * MB);      // 512 KiB [1024][256] (contiguous after WukT)
  bf16* ctx   = xbf;

  // 1 prep launch: x->bf16, 5 weight transposes, Wkv=bf16(Wk+Wv)
  prep_kernel<<<5376, 256, 0, stream>>>(x, Wq, Wk, Wv, Wo, Wdn, Wuk, Wuv,
                                        xbf, WqT, WoT, WdnT, WukT, WuvT, Wkv);
  // q = x@Wq  (256 blocks)  +  WkvdT = Wdn^T @ (Wk+Wv)^T  (16 blocks)
  gemm_q_w<<<272, 256, 0, stream>>>(xbf, WqT, qbf, WdnT, Wkv, WkvdT);
  // latent = x @ Wkvd  -> bf16 scratch + f32 OUTPUT 1
  gemm_latent<<<256, 256, 0, stream>>>(xbf, WkvdT, latbf, out_lat);
  // k_rec = latent @ W_up_k ; v_rec^T = (latent @ W_up_v)^T   (one fused launch)
  gemm_up<<<512, 256, 0, stream>>>(latbf, WukT, kbuf, vT);
  // attention
  attn_kernel<<<dim3(SEQ / 64, NH, NB), 256, 0, stream>>>(qbf, kbuf, vT, ctx);
  // out0 = ctx @ Wo
  gemm_out<<<256, 256, 0, stream>>>(ctx, WoT, out0);

  (void)in_sizes; (void)n_in; (void)out_size; (void)ws_size;
}